// Round 13
// baseline (336.195 us; speedup 1.0000x reference)
//
#include <hip/hip_runtime.h>
#include <hip/hip_cooperative_groups.h>
#include <math.h>

namespace cg = cooperative_groups;

#define NN 50000
#define RR 32
#define HH 16
#define CC 8
#define SHIFT 6
#define BSZ 64                       // dsts per bucket
#define NB 782                       // ceil(NN/BSZ)
#define CAP 2560                     // fixed bucket capacity (mean 2048, sigma 45)
#define G 256                        // cooperative grid blocks
#define BINS (BSZ * RR)              // 2048 per-bucket (dl,r) bins
#define SCH 64                       // nodes per hwbuild block

static __device__ __forceinline__ unsigned short f2bf(float x) {
    unsigned u = __float_as_uint(x);
    unsigned r = (u + 0x7FFF + ((u >> 16) & 1)) >> 16;
    return (unsigned short)r;
}

// ---------------- fused CSR build (cooperative): hist -> scan -> scatter -> sort ----

__global__ __launch_bounds__(256) void build_k(
        const int* __restrict__ src, const int* __restrict__ dst,
        const int* __restrict__ et, int* __restrict__ hist, int* __restrict__ pos,
        int* __restrict__ btot, unsigned* __restrict__ bucket,
        unsigned* __restrict__ sorted, int* __restrict__ off2,
        float* __restrict__ inv, int E) {
    __shared__ int smem[BINS];       // lh (A) / cur (C) / bins (D)
    __shared__ unsigned stage[CAP];
    __shared__ int ts[256];
    cg::grid_group grid = cg::this_grid();
    int g = blockIdx.x, t = threadIdx.x;
    int chunk = (E + G - 1) / G;
    int beg = g * chunk, end = min(beg + chunk, E);

    // ---- phase A: per-block histogram ----
    for (int j = t; j < NB; j += 256) smem[j] = 0;
    __syncthreads();
    for (int i = beg + t; i < end; i += 256)
        atomicAdd(&smem[dst[i] >> SHIFT], 1);
    __syncthreads();
    for (int j = t; j < NB; j += 256) hist[g * NB + j] = smem[j];
    __threadfence();
    grid.sync();

    // ---- phase B: per-bucket prefix over blocks (first NB global threads) ----
    int T = g * 256 + t;
    if (T < NB) {
        int run = T * CAP;
        for (int gg = 0; gg < G; ++gg) {
            pos[gg * NB + T] = run;
            run += hist[gg * NB + T];
        }
        btot[T] = run - T * CAP;
    }
    __threadfence();
    grid.sync();

    // ---- phase C: scatter with LDS cursors ----
    for (int j = t; j < NB; j += 256) smem[j] = pos[g * NB + j];
    __syncthreads();
    for (int i = beg + t; i < end; i += 256) {
        int d = dst[i];
        int p = atomicAdd(&smem[d >> SHIFT], 1);
        bucket[p] = (unsigned)src[i] | ((unsigned)et[i] << 16) |
                    ((unsigned)(d & (BSZ - 1)) << 21);
    }
    __threadfence();
    grid.sync();

    // ---- phase D: per-bucket counting sort by (dl,r); blocks stride buckets ----
    for (int b = g; b < NB; b += G) {
        int e0 = b * CAP, n = btot[b];
        int d0 = b * BSZ;
        int ndst = NN - d0; if (ndst > BSZ) ndst = BSZ;
        __syncthreads();
        for (int j = t; j < BINS; j += 256) smem[j] = 0;
        __syncthreads();
        for (int i = t; i < n; i += 256) {
            unsigned rec = bucket[e0 + i];
            int key = ((rec >> 21) & 63) * RR + ((rec >> 16) & 31);
            atomicAdd(&smem[key], 1);
        }
        __syncthreads();
        for (int j = t; j < ndst * RR; j += 256)
            inv[d0 * RR + j] = 1.0f / fmaxf((float)smem[j], 1.0f);
        int loc[8]; int s = 0;
#pragma unroll
        for (int k = 0; k < 8; ++k) { loc[k] = smem[t * 8 + k]; s += loc[k]; }
        ts[t] = s;
        __syncthreads();
        for (int ofs = 1; ofs < 256; ofs <<= 1) {
            int add = (t >= ofs) ? ts[t - ofs] : 0;
            __syncthreads();
            ts[t] += add;
            __syncthreads();
        }
        int run = ts[t] - s;
        __syncthreads();
#pragma unroll
        for (int k = 0; k < 8; ++k) { int c = loc[k]; smem[t * 8 + k] = run; run += c; }
        __syncthreads();
        for (int dl = t; dl < BSZ; dl += 256) off2[b * 65 + dl] = e0 + smem[dl * RR];
        if (t == 0) off2[b * 65 + 64] = e0 + n;
        __syncthreads();
        for (int i = t; i < n; i += 256) {
            unsigned rec = bucket[e0 + i];
            int key = ((rec >> 21) & 63) * RR + ((rec >> 16) & 31);
            int p = atomicAdd(&smem[key], 1);
            stage[p] = rec & 0x1FFFFF;
        }
        __syncthreads();
        for (int i = t; i < n; i += 256) sorted[e0 + i] = stage[i];
    }
}

// ---------------- layer 1: wave-per-dst, 4-slot prefetched gather ----------------

__global__ __launch_bounds__(256) void layer1_k(
        const unsigned* __restrict__ sorted, const int* __restrict__ off2,
        const float* __restrict__ inv, const float4* __restrict__ w1v,
        const float4* __restrict__ root1v, const float4* __restrict__ bias1v,
        float4* __restrict__ hv) {
    int d = (blockIdx.x * blockDim.x + threadIdx.x) >> 6;
    if (d >= NN) return;
    int lane = threadIdx.x & 63;
    int q = lane & 3, eo = lane >> 2;
    int idx = (d >> 6) * 65 + (d & 63);
    int b0 = off2[idx], b1 = off2[idx + 1];
    const float* invd = inv + d * RR;

    unsigned rec[4]; float sc[4];
#pragma unroll
    for (int k = 0; k < 4; ++k) {
        int i = b0 + eo + k * 16;
        bool ok = i < b1;
        rec[k] = ok ? sorted[i] : 0u;
        sc[k]  = ok ? invd[(rec[k] >> 16) & 31] : 0.f;
    }
    float4 w[4];
#pragma unroll
    for (int k = 0; k < 4; ++k)
        w[k] = w1v[(size_t)(((rec[k] >> 16) & 31) * NN + (rec[k] & 0xFFFF)) * 4 + q];
    float ax = 0.f, ay = 0.f, az = 0.f, aw = 0.f;
#pragma unroll
    for (int k = 0; k < 4; ++k) {
        ax += w[k].x * sc[k]; ay += w[k].y * sc[k];
        az += w[k].z * sc[k]; aw += w[k].w * sc[k];
    }
    for (int i = b0 + 64 + eo; i < b1; i += 16) {
        unsigned rr = sorted[i];
        float s2 = invd[(rr >> 16) & 31];
        float4 ww = w1v[(size_t)(((rr >> 16) & 31) * NN + (rr & 0xFFFF)) * 4 + q];
        ax += ww.x * s2; ay += ww.y * s2; az += ww.z * s2; aw += ww.w * s2;
    }
#pragma unroll
    for (int m = 4; m < 64; m <<= 1) {
        ax += __shfl_xor(ax, m); ay += __shfl_xor(ay, m);
        az += __shfl_xor(az, m); aw += __shfl_xor(aw, m);
    }
    if (lane < 4) {
        float4 rt = root1v[d * 4 + lane];
        float4 bs = bias1v[lane];
        float4 o;
        o.x = fmaxf(ax + rt.x + bs.x, 0.f);
        o.y = fmaxf(ay + rt.y + bs.y, 0.f);
        o.z = fmaxf(az + rt.z + bs.z, 0.f);
        o.w = fmaxf(aw + rt.w + bs.w, 0.f);
        hv[d * 4 + lane] = o;
    }
}

// ---------------- hw precompute (bf16): hw2u[s*128 + r*4 + cp] = pack(c=2cp, 2cp+1) ----

__global__ __launch_bounds__(256) void hwbuild_k(
        const float* __restrict__ h, const float* __restrict__ w2,
        unsigned* __restrict__ hw2u) {
    __shared__ float4 hs[SCH * 4];   // 64 nodes x 16 ch
    int tid = threadIdx.x;
    int nl = tid >> 7;               // node-lane 0/1
    int k  = tid & 127;              // r*4 + cpair
    int r  = k >> 2;
    int c0 = (k & 3) * 2;
    float wa[HH], wb[HH];
    {
        const float* base = w2 + r * HH * CC;
#pragma unroll
        for (int f = 0; f < HH; ++f) {
            wa[f] = base[f * CC + c0];
            wb[f] = base[f * CC + c0 + 1];
        }
    }
    int s0 = blockIdx.x * SCH;
    int nnodes = NN - s0; if (nnodes > SCH) nnodes = SCH;
    const float4* hg = (const float4*)(h + s0 * HH);
    for (int j = tid; j < nnodes * 4; j += 256) hs[j] = hg[j];
    __syncthreads();
    for (int sl = nl; sl < nnodes; sl += 2) {
        float4 h0 = hs[sl * 4 + 0], h1 = hs[sl * 4 + 1];
        float4 h2 = hs[sl * 4 + 2], h3 = hs[sl * 4 + 3];
        float hr[HH] = {h0.x, h0.y, h0.z, h0.w, h1.x, h1.y, h1.z, h1.w,
                        h2.x, h2.y, h2.z, h2.w, h3.x, h3.y, h3.z, h3.w};
        float va = 0.f, vb = 0.f;
#pragma unroll
        for (int f = 0; f < HH; ++f) { va += hr[f] * wa[f]; vb += hr[f] * wb[f]; }
        unsigned packed = (unsigned)f2bf(va) | ((unsigned)f2bf(vb) << 16);
        hw2u[(size_t)(s0 + sl) * 128 + k] = packed;
    }
}

// ---------------- layer 2: wave-per-dst, 4-slot prefetched gather over bf16 pairs ----

__global__ __launch_bounds__(256) void layer2_k(
        const unsigned* __restrict__ sorted, const int* __restrict__ off2,
        const float* __restrict__ inv, const unsigned* __restrict__ hw2u,
        const float* __restrict__ h, const float* __restrict__ root2,
        const float* __restrict__ bias2, float* __restrict__ out) {
    int d = (blockIdx.x * blockDim.x + threadIdx.x) >> 6;
    if (d >= NN) return;
    int lane = threadIdx.x & 63;
    int sub = lane >> 2, cp = lane & 3;
    int idx = (d >> 6) * 65 + (d & 63);
    int b0 = off2[idx], b1 = off2[idx + 1];
    const float* invd = inv + d * RR;

    unsigned rec[4]; float sc[4];
#pragma unroll
    for (int k = 0; k < 4; ++k) {
        int i = b0 + sub + k * 16;
        bool ok = i < b1;
        rec[k] = ok ? sorted[i] : 0u;
        sc[k]  = ok ? invd[(rec[k] >> 16) & 31] : 0.f;
    }
    unsigned pk[4];
#pragma unroll
    for (int k = 0; k < 4; ++k)
        pk[k] = hw2u[(size_t)(rec[k] & 0xFFFF) * 128 + ((rec[k] >> 16) & 31) * 4 + cp];
    float alo = 0.f, ahi = 0.f;
#pragma unroll
    for (int k = 0; k < 4; ++k) {
        alo += __uint_as_float(pk[k] << 16) * sc[k];
        ahi += __uint_as_float(pk[k] & 0xFFFF0000u) * sc[k];
    }
    for (int i = b0 + 64 + sub; i < b1; i += 16) {
        unsigned rr = sorted[i];
        float s2 = invd[(rr >> 16) & 31];
        unsigned pp = hw2u[(size_t)(rr & 0xFFFF) * 128 + ((rr >> 16) & 31) * 4 + cp];
        alo += __uint_as_float(pp << 16) * s2;
        ahi += __uint_as_float(pp & 0xFFFF0000u) * s2;
    }
#pragma unroll
    for (int m = 4; m < 64; m <<= 1) {
        alo += __shfl_xor(alo, m);
        ahi += __shfl_xor(ahi, m);
    }
    if (lane < 4) {
        int c0 = cp * 2;
        float vlo = alo + bias2[c0];
        float vhi = ahi + bias2[c0 + 1];
        const float* hd = h + d * HH;
#pragma unroll
        for (int f = 0; f < HH; ++f) {
            float hf = hd[f];
            vlo += hf * root2[f * CC + c0];
            vhi += hf * root2[f * CC + c0 + 1];
        }
        float m = fmaxf(vlo, vhi);
        m = fmaxf(m, __shfl_xor(m, 1));
        m = fmaxf(m, __shfl_xor(m, 2));
        float ss = expf(vlo - m) + expf(vhi - m);
        ss += __shfl_xor(ss, 1);
        ss += __shfl_xor(ss, 2);
        float z = m + logf(ss);
        float2 o = make_float2(vlo - z, vhi - z);
        *(float2*)(out + d * CC + c0) = o;
    }
}

// ---------------- launch ----------------

extern "C" void kernel_launch(void* const* d_in, const int* in_sizes, int n_in,
                              void* d_out, int out_size, void* d_ws, size_t ws_size,
                              hipStream_t stream) {
    const int*   edge_index = (const int*)d_in[0];
    const int*   edge_type  = (const int*)d_in[1];
    const float* weight1    = (const float*)d_in[2];
    const float* root1      = (const float*)d_in[3];
    const float* bias1      = (const float*)d_in[4];
    const float* weight2    = (const float*)d_in[5];
    const float* root2      = (const float*)d_in[6];
    const float* bias2      = (const float*)d_in[7];
    float* out = (float*)d_out;

    const int E = in_sizes[1];
    const int* src = edge_index;
    const int* dst = edge_index + E;

    // ---- workspace layout with aliasing ----
    char* base = (char*)d_ws;
    size_t hw2_bytes = sizeof(unsigned short) * (size_t)NN * RR * CC;  // 25.6 MB
    unsigned* hw2u = (unsigned*)base;

    char* p = base;
    auto suballoc = [&](size_t bytes) -> void* {
        void* r = (void*)p; p += (bytes + 255) & ~(size_t)255; return r;
    };
    int*      hist   = (int*)     suballoc(sizeof(int) * (size_t)G * NB);        // 0.8 MB
    int*      pos    = (int*)     suballoc(sizeof(int) * (size_t)G * NB);        // 0.8 MB
    unsigned* bucket = (unsigned*)suballoc(sizeof(unsigned) * (size_t)NB * CAP); // 8.0 MB

    p = base + ((hw2_bytes + 255) & ~(size_t)255);
    int*      btot   = (int*)     suballoc(sizeof(int) * NB);
    int*      off2   = (int*)     suballoc(sizeof(int) * (size_t)NB * 65);
    unsigned* sorted = (unsigned*)suballoc(sizeof(unsigned) * (size_t)NB * CAP); // 8.0 MB
    float*    inv    = (float*)   suballoc(sizeof(float) * (size_t)NN * RR);     // 6.4 MB
    float*    h      = (float*)   suballoc(sizeof(float) * (size_t)NN * HH);     // 3.2 MB
    (void)ws_size;

    int E_ = E;
    void* args[] = {(void*)&src, (void*)&dst, (void*)&edge_type,
                    (void*)&hist, (void*)&pos, (void*)&btot,
                    (void*)&bucket, (void*)&sorted, (void*)&off2,
                    (void*)&inv, (void*)&E_};
    hipLaunchCooperativeKernel((void*)build_k, dim3(G), dim3(256), args, 0, stream);

    int nblk = (NN * 64 + 255) / 256;   // one wave per dst
    layer1_k<<<nblk, 256, 0, stream>>>(sorted, off2, inv, (const float4*)weight1,
                                       (const float4*)root1, (const float4*)bias1,
                                       (float4*)h);
    hwbuild_k<<<(NN + SCH - 1) / SCH, 256, 0, stream>>>(h, weight2, hw2u);
    layer2_k<<<nblk, 256, 0, stream>>>(sorted, off2, inv, hw2u, h,
                                       root2, bias2, out);
}